// Round 8
// baseline (102.284 us; speedup 1.0000x reference)
//
#include <hip/hip_runtime.h>

// LabPool: out[d,l] = max_n( labmap[l,n] * X[d,n] ), labmap one-hot over l.
// Zeros always participate -> out[d,l] = max(0, max_{label(n)=l} X[d,n]).
// Non-negative results -> uint bit ordering == float ordering (ds_max_u32).
//
// Locked-in lessons:
//  - NO hipLaunchCooperativeKernel (R4: HBM collapsed to 240 GB/s, 6x).
//  - lane = feature d, label wave-uniform at use (readlane) -> conflict-free DS.
//  - depth-2 register prefetch + double-buffered Xs, one barrier per tile.
//  - R7 lesson: main kernel is at its HBM/latency floor; remaining cost is
//    the SECOND dispatch. This round: single dispatch, threadfence-reduction.
//
// Ticket invariant: each executed call adds exactly NB (=512, pow2) to
// g_ticket, so g_ticket % NB == 0 at every call start (module-load zero-init;
// graph capture does not execute). target = (old & ~(NB-1)) + NB; wrap-safe
// signed compare. No ws state, no resets, deterministic output.

constexpr int L = 32;
constexpr int D = 64;            // == wave size
constexpr int TI = 64;           // items/tile; 200000/64 = 3125 tiles
constexpr int NB = 512;          // blocks (2/CU, co-resident), power of 2
constexpr int NT = 512;          // threads/block (8 waves)
constexpr int XS_STRIDE = 65;    // LDS X-tile row stride (2-way banks = free)
constexpr int SM_STRIDE = 33;    // LDS table row stride (2-way banks = free)
constexpr int SM_SIZE = D * SM_STRIDE;  // 2112
constexpr int TBL = D * L;       // packed global table (2048 u32)

__device__ unsigned g_ticket = 0;   // monotone; % NB == 0 at call boundaries

__device__ __forceinline__ uint4 max4(uint4 a, uint4 b)
{
    a.x = (b.x > a.x) ? b.x : a.x;
    a.y = (b.y > a.y) ? b.y : a.y;
    a.z = (b.z > a.z) ? b.z : a.z;
    a.w = (b.w > a.w) ? b.w : a.w;
    return a;
}

__global__ __launch_bounds__(NT, 4)
void labpool_fused(const float* __restrict__ labmap,
                   const float* __restrict__ X,
                   unsigned* __restrict__ tables,
                   float* __restrict__ out,
                   int N, int ntiles)
{
    __shared__ __attribute__((aligned(16))) float Xs[2][D * XS_STRIDE]; // 33 KB
    __shared__ unsigned sm[SM_SIZE];                                    // 8.4 KB

    const int tid  = threadIdx.x;
    const int wave = tid >> 6;
    const int lane = tid & 63;
    const int item  = lane & 7;              // decode: wave covers items wave*8..+7
    const int lrow0 = (lane >> 3) << 2;      // decode: 4 labmap rows per 8-lane group

    for (int i = tid; i < SM_SIZE; i += NT) sm[i] = 0u;

    if ((int)blockIdx.x < ntiles) {
        const int r0 = tid >> 4;             // staging rows 0..31
        const int c0 = 4 * (tid & 15);
        const int r1 = r0 + 32;              // staging rows 32..63
        const size_t rowOff0 = (size_t)r0 * N + c0;
        const size_t rowOff1 = (size_t)r1 * N + c0;
        const float* mbase = labmap + (size_t)lrow0 * N + wave * 8 + item;

        const int laneX = lane * XS_STRIDE + wave * 8;
        const int laneS = lane * SM_STRIDE;

        float4 xr0, xr1;                     // single X register slot
        auto LOAD = [&](int t, float (&m)[4]) {
            const int n0 = t * TI;
            xr0 = *reinterpret_cast<const float4*>(X + rowOff0 + n0);
            xr1 = *reinterpret_cast<const float4*>(X + rowOff1 + n0);
            const float* mp = mbase + n0;
            m[0] = mp[0];
            m[1] = mp[(size_t)N];
            m[2] = mp[(size_t)2 * N];
            m[3] = mp[(size_t)3 * N];
        };
        auto STAGE = [&](int b) {
            *reinterpret_cast<float4*>(&Xs[b][r0 * XS_STRIDE + c0]) = xr0;
            *reinterpret_cast<float4*>(&Xs[b][r1 * XS_STRIDE + c0]) = xr1;
        };
        auto LABV = [&](const float (&m)[4]) -> unsigned {
            float acc =            (float)(lrow0)     * m[0];
            acc = fmaf((float)(lrow0 + 1), m[1], acc);
            acc = fmaf((float)(lrow0 + 2), m[2], acc);
            acc = fmaf((float)(lrow0 + 3), m[3], acc);
            acc += __shfl_xor(acc, 8);           // sum the 8 row-groups
            acc += __shfl_xor(acc, 16);
            acc += __shfl_xor(acc, 32);
            return (unsigned)acc;                // exact small int
        };
        auto CONSUME = [&](int b, unsigned labv) {
#pragma unroll
            for (int j = 0; j < 8; ++j) {
                const int labj = __builtin_amdgcn_readlane((int)labv, j);
                const float x = Xs[b][laneX + j];
                atomicMax(&sm[laneS + labj], __float_as_uint(fmaxf(x, 0.f)));
            }
        };

        int t = blockIdx.x;
        float mA[4], mB[4];
        LOAD(t, mA);
        STAGE(0);
        unsigned lvA = LABV(mA);
        bool h1 = (t + NB < ntiles);
        if (h1) LOAD(t + NB, mB);
        __syncthreads();                         // buf0 ready

        while (true) {
            if (h1) STAGE(1);
            const unsigned lvB = h1 ? LABV(mB) : 0u;
            if (t + 2 * NB < ntiles) LOAD(t + 2 * NB, mA);
            CONSUME(0, lvA);
            __syncthreads();
            if (!h1) break;
            t += NB;
            h1 = (t + NB < ntiles);

            if (h1) STAGE(0);
            lvA = h1 ? LABV(mA) : 0u;
            if (t + 2 * NB < ntiles) LOAD(t + 2 * NB, mB);
            CONSUME(1, lvB);
            __syncthreads();
            if (!h1) break;
            t += NB;
            h1 = (t + NB < ntiles);
        }
        __syncthreads();                         // drain all waves' sm atomics
    } else {
        __syncthreads();                         // zero table path
    }

    // ---- publish this block's packed table ----
    unsigned* dst = tables + (size_t)blockIdx.x * TBL;
    for (int i = tid; i < TBL; i += NT)
        dst[i] = sm[(i >> 5) * SM_STRIDE + (i & 31)];

    __threadfence();                             // release tables (device scope)
    if (tid == 0) {
        const unsigned old = atomicAdd(&g_ticket, 1u);
        if (blockIdx.x < (unsigned)D) {
            const unsigned target = (old & ~(unsigned)(NB - 1)) + (unsigned)NB;
            while ((int)(__hip_atomic_load(&g_ticket, __ATOMIC_ACQUIRE,
                                           __HIP_MEMORY_SCOPE_AGENT) - target) < 0)
                __builtin_amdgcn_s_sleep(2);
        }
    }
    if (blockIdx.x >= (unsigned)D) return;

    __syncthreads();                             // block released by tid0's spin
    __threadfence();                             // acquire: invalidate caches

    // ---- tail reduce: this block owns feature row d = blockIdx.x ----
    const int d    = blockIdx.x;
    const int part = tid & 7;                    // 8 x uint4 = 32 labels
    const int g    = tid >> 3;                   // 64 table-groups
    const unsigned* tb = tables + d * L + part * 4;

    uint4 m = make_uint4(0u, 0u, 0u, 0u);
#pragma unroll 8
    for (int b = g; b < NB; b += 64)
        m = max4(m, *reinterpret_cast<const uint4*>(tb + (size_t)b * TBL));

    uint4* red = reinterpret_cast<uint4*>(&Xs[0][0]);   // reuse LDS (8 KB)
    red[tid] = m;
    __syncthreads();
#pragma unroll
    for (int s = NT / 2; s >= 8; s >>= 1) {
        if (tid < s) red[tid] = max4(red[tid], red[tid + s]);
        __syncthreads();
    }
    if (tid < 8) {
        const uint4 r = red[tid];
        float4 f;
        f.x = __uint_as_float(r.x);
        f.y = __uint_as_float(r.y);
        f.z = __uint_as_float(r.z);
        f.w = __uint_as_float(r.w);
        *reinterpret_cast<float4*>(out + d * L + tid * 4) = f;
    }
}

// ---- fallback (tiny ws): fused kernel with global atomics ----
__global__ __launch_bounds__(256)
void labpool_fused_atomic(const float* __restrict__ labmap,
                          const float* __restrict__ X,
                          unsigned* __restrict__ gout, int N)
{
    __shared__ unsigned sm2[D * L];
    __shared__ unsigned char lab[400];
    const int tid = threadIdx.x;
    const int n0 = blockIdx.x * 400;
    for (int i = tid; i < D * L; i += 256) sm2[i] = 0u;
    constexpr int V = 100;
    for (int idx = tid; idx < L * V; idx += 256) {
        const int l = idx / V;
        const int v = idx - l * V;
        const float4 m = *reinterpret_cast<const float4*>(labmap + (size_t)l * N + n0 + 4 * v);
        if (m.x > 0.5f) lab[4 * v + 0] = (unsigned char)l;
        if (m.y > 0.5f) lab[4 * v + 1] = (unsigned char)l;
        if (m.z > 0.5f) lab[4 * v + 2] = (unsigned char)l;
        if (m.w > 0.5f) lab[4 * v + 3] = (unsigned char)l;
    }
    __syncthreads();
    for (int idx = tid; idx < D * V; idx += 256) {
        const int d = idx / V;
        const int v = idx - d * V;
        const float4 x = *reinterpret_cast<const float4*>(X + (size_t)d * N + n0 + 4 * v);
        const uchar4 lv = *reinterpret_cast<const uchar4*>(&lab[4 * v]);
        atomicMax(&sm2[d * L + lv.x], __float_as_uint(fmaxf(x.x, 0.f)));
        atomicMax(&sm2[d * L + lv.y], __float_as_uint(fmaxf(x.y, 0.f)));
        atomicMax(&sm2[d * L + lv.z], __float_as_uint(fmaxf(x.z, 0.f)));
        atomicMax(&sm2[d * L + lv.w], __float_as_uint(fmaxf(x.w, 0.f)));
    }
    __syncthreads();
    for (int i = tid; i < D * L; i += 256) atomicMax(&gout[i], sm2[i]);
}

__global__ void zero_out_k(unsigned* p, int n)
{
    const int i = blockIdx.x * 256 + threadIdx.x;
    if (i < n) p[i] = 0u;
}

extern "C" void kernel_launch(void* const* d_in, const int* in_sizes, int n_in,
                              void* d_out, int out_size, void* d_ws, size_t ws_size,
                              hipStream_t stream)
{
    const float* labmap = (const float*)d_in[0];   // [L, N]
    const float* X      = (const float*)d_in[1];   // [D, N]
    const int N = in_sizes[0] / L;                 // 200000
    const int ntiles = N / TI;                     // 3125

    const size_t need = (size_t)NB * TBL * sizeof(unsigned);  // 4.2 MB
    if (d_ws && ws_size >= need && (N % TI) == 0) {
        unsigned* tables = (unsigned*)d_ws;
        labpool_fused<<<NB, NT, 0, stream>>>(labmap, X, tables, (float*)d_out,
                                             N, ntiles);
    } else {
        unsigned* gout = (unsigned*)d_out;
        zero_out_k<<<(D * L + 255) / 256, 256, 0, stream>>>(gout, D * L);
        labpool_fused_atomic<<<N / 400, 256, 0, stream>>>(labmap, X, gout, N);
    }
}

// Round 9
// 23.390 us; speedup vs baseline: 4.3730x; 4.3730x over previous
//
#include <hip/hip_runtime.h>

// LabPool: out[d,l] = max_n( labmap[l,n] * X[d,n] ), labmap one-hot over l.
// Zeros always participate -> out[d,l] = max(0, max_{label(n)=l} X[d,n]).
// Non-negative results -> uint bit ordering == float ordering (ds_max_u32).
//
// Locked-in lessons:
//  - NO in-kernel cross-block handoff: per-block device-scope release fences
//    serialize L2 writebacks at ~0.25us/block (R4: 768 blk -> 204us; R8:
//    512 blk -> 112us). Kernel boundary = one flush, ~free. Two dispatches.
//  - lane = feature d, label wave-uniform at use (readlane) -> conflict-free DS.
//  - depth-2 register prefetch + double-buffered Xs, one barrier per tile (R7).
//  - Inputs are L3-resident during timed replays (R8: FETCH 39.6MB < 77MB) ->
//    main kernel is latency-bound, not HBM-bound. This round: 3 blocks/CU.

constexpr int L = 32;
constexpr int D = 64;            // == wave size
constexpr int TI = 64;           // items/tile; 200000/64 = 3125 tiles
constexpr int NB = 768;          // blocks (3/CU co-resident)
constexpr int NT = 512;          // threads/block (8 waves)
constexpr int XS_STRIDE = 65;    // LDS X-tile row stride (2-way banks = free)
constexpr int SM_STRIDE = 33;    // LDS table row stride (2-way banks = free)
constexpr int SM_SIZE = D * SM_STRIDE;  // 2112
constexpr int TBL = D * L;       // packed global table (2048 u32)

__global__ __launch_bounds__(NT, 6)
void labpool_main(const float* __restrict__ labmap,
                  const float* __restrict__ X,
                  unsigned* __restrict__ tables, int N, int ntiles)
{
    __shared__ __attribute__((aligned(16))) float Xs[2][D * XS_STRIDE]; // 33 KB
    __shared__ unsigned sm[SM_SIZE];                                    // 8.4 KB

    const int tid  = threadIdx.x;
    const int wave = tid >> 6;
    const int lane = tid & 63;
    const int item  = lane & 7;              // decode: wave covers items wave*8..+7
    const int lrow0 = (lane >> 3) << 2;      // decode: 4 labmap rows per 8-lane group

    unsigned* dst = tables + (size_t)blockIdx.x * TBL;
    if ((int)blockIdx.x >= ntiles) {         // no tiles: emit zero table
        for (int i = tid; i < TBL; i += NT) dst[i] = 0u;
        return;
    }

    for (int i = tid; i < SM_SIZE; i += NT) sm[i] = 0u;

    const int r0 = tid >> 4;                 // staging rows 0..31
    const int c0 = 4 * (tid & 15);
    const int r1 = r0 + 32;                  // staging rows 32..63
    const size_t rowOff0 = (size_t)r0 * N + c0;
    const size_t rowOff1 = (size_t)r1 * N + c0;
    const float* mbase = labmap + (size_t)lrow0 * N + wave * 8 + item;

    const int laneX = lane * XS_STRIDE + wave * 8;
    const int laneS = lane * SM_STRIDE;

    float4 xr0, xr1;                         // single X register slot
    auto LOAD = [&](int t, float (&m)[4]) {
        const int n0 = t * TI;
        xr0 = *reinterpret_cast<const float4*>(X + rowOff0 + n0);
        xr1 = *reinterpret_cast<const float4*>(X + rowOff1 + n0);
        const float* mp = mbase + n0;
        m[0] = mp[0];
        m[1] = mp[(size_t)N];
        m[2] = mp[(size_t)2 * N];
        m[3] = mp[(size_t)3 * N];
    };
    auto STAGE = [&](int b) {
        *reinterpret_cast<float4*>(&Xs[b][r0 * XS_STRIDE + c0]) = xr0;
        *reinterpret_cast<float4*>(&Xs[b][r1 * XS_STRIDE + c0]) = xr1;
    };
    auto LABV = [&](const float (&m)[4]) -> unsigned {
        float acc =            (float)(lrow0)     * m[0];
        acc = fmaf((float)(lrow0 + 1), m[1], acc);
        acc = fmaf((float)(lrow0 + 2), m[2], acc);
        acc = fmaf((float)(lrow0 + 3), m[3], acc);
        acc += __shfl_xor(acc, 8);               // sum the 8 row-groups
        acc += __shfl_xor(acc, 16);
        acc += __shfl_xor(acc, 32);
        return (unsigned)acc;                    // exact small int
    };
    auto CONSUME = [&](int b, unsigned labv) {
#pragma unroll
        for (int j = 0; j < 8; ++j) {
            const int labj = __builtin_amdgcn_readlane((int)labv, j); // wave-uniform
            const float x = Xs[b][laneX + j];                          // 2-way banks
            atomicMax(&sm[laneS + labj], __float_as_uint(fmaxf(x, 0.f)));
        }
    };

    // ---- prologue: stage tile t into buf0, prefetch tile t+NB ----
    int t = blockIdx.x;
    float mA[4], mB[4];
    LOAD(t, mA);
    STAGE(0);
    unsigned lvA = LABV(mA);
    bool h1 = (t + NB < ntiles);
    if (h1) LOAD(t + NB, mB);
    __syncthreads();                             // buf0 ready

    while (true) {
        // ---- consume buf0 (tile t); stage tile t+NB -> buf1 ----
        if (h1) STAGE(1);                        // X regs hold tile t+NB
        const unsigned lvB = h1 ? LABV(mB) : 0u;
        if (t + 2 * NB < ntiles) LOAD(t + 2 * NB, mA);   // issue early
        CONSUME(0, lvA);
        __syncthreads();                         // stage(t+NB) done + consume(t) done
        if (!h1) break;
        t += NB;
        h1 = (t + NB < ntiles);

        // ---- consume buf1 (tile t); stage tile t+NB -> buf0 ----
        if (h1) STAGE(0);                        // X regs hold tile t+NB
        lvA = h1 ? LABV(mA) : 0u;
        if (t + 2 * NB < ntiles) LOAD(t + 2 * NB, mB);
        CONSUME(1, lvB);
        __syncthreads();
        if (!h1) break;
        t += NB;
        h1 = (t + NB < ntiles);
    }

    __syncthreads();                             // drain all waves' sm atomics
    for (int i = tid; i < TBL; i += NT)
        dst[i] = sm[(i >> 5) * SM_STRIDE + (i & 31)];   // unpad on the way out
}

__global__ __launch_bounds__(256)
void labpool_reduce(const unsigned* __restrict__ tables, float* __restrict__ out, int nb)
{
    // 128 blocks: block = (d, half). Each handles 16 labels = 4 uint4 parts.
    __shared__ uint4 red[256];
    const int tid  = threadIdx.x;
    const int d    = blockIdx.x >> 1;
    const int h    = blockIdx.x & 1;
    const int part = tid & 3;
    const int g    = tid >> 2;                   // 64 table-groups
    const int base = d * L + h * 16 + part * 4;  // 16-B aligned

    uint4 m = make_uint4(0u, 0u, 0u, 0u);
    for (int b = g; b < nb; b += 64) {
        const uint4 v = *reinterpret_cast<const uint4*>(tables + (size_t)b * TBL + base);
        m.x = (v.x > m.x) ? v.x : m.x;
        m.y = (v.y > m.y) ? v.y : m.y;
        m.z = (v.z > m.z) ? v.z : m.z;
        m.w = (v.w > m.w) ? v.w : m.w;
    }
    red[tid] = m;
    __syncthreads();
#pragma unroll
    for (int s = 128; s >= 4; s >>= 1) {
        if (tid < s) {
            const uint4 v = red[tid + s];
            uint4 r = red[tid];
            r.x = (v.x > r.x) ? v.x : r.x;
            r.y = (v.y > r.y) ? v.y : r.y;
            r.z = (v.z > r.z) ? v.z : r.z;
            r.w = (v.w > r.w) ? v.w : r.w;
            red[tid] = r;
        }
        __syncthreads();
    }
    if (tid < 4) {
        const uint4 r = red[tid];
        float4 f;
        f.x = __uint_as_float(r.x);
        f.y = __uint_as_float(r.y);
        f.z = __uint_as_float(r.z);
        f.w = __uint_as_float(r.w);
        *reinterpret_cast<float4*>(out + d * L + h * 16 + tid * 4) = f;
    }
}

// ---- fallback (tiny ws): fused kernel with global atomics ----
__global__ __launch_bounds__(256)
void labpool_fused_atomic(const float* __restrict__ labmap,
                          const float* __restrict__ X,
                          unsigned* __restrict__ gout, int N)
{
    __shared__ unsigned sm2[D * L];
    __shared__ unsigned char lab[400];
    const int tid = threadIdx.x;
    const int n0 = blockIdx.x * 400;
    for (int i = tid; i < D * L; i += 256) sm2[i] = 0u;
    constexpr int V = 100;
    for (int idx = tid; idx < L * V; idx += 256) {
        const int l = idx / V;
        const int v = idx - l * V;
        const float4 m = *reinterpret_cast<const float4*>(labmap + (size_t)l * N + n0 + 4 * v);
        if (m.x > 0.5f) lab[4 * v + 0] = (unsigned char)l;
        if (m.y > 0.5f) lab[4 * v + 1] = (unsigned char)l;
        if (m.z > 0.5f) lab[4 * v + 2] = (unsigned char)l;
        if (m.w > 0.5f) lab[4 * v + 3] = (unsigned char)l;
    }
    __syncthreads();
    for (int idx = tid; idx < D * V; idx += 256) {
        const int d = idx / V;
        const int v = idx - d * V;
        const float4 x = *reinterpret_cast<const float4*>(X + (size_t)d * N + n0 + 4 * v);
        const uchar4 lv = *reinterpret_cast<const uchar4*>(&lab[4 * v]);
        atomicMax(&sm2[d * L + lv.x], __float_as_uint(fmaxf(x.x, 0.f)));
        atomicMax(&sm2[d * L + lv.y], __float_as_uint(fmaxf(x.y, 0.f)));
        atomicMax(&sm2[d * L + lv.z], __float_as_uint(fmaxf(x.z, 0.f)));
        atomicMax(&sm2[d * L + lv.w], __float_as_uint(fmaxf(x.w, 0.f)));
    }
    __syncthreads();
    for (int i = tid; i < D * L; i += 256) atomicMax(&gout[i], sm2[i]);
}

__global__ void zero_out_k(unsigned* p, int n)
{
    const int i = blockIdx.x * 256 + threadIdx.x;
    if (i < n) p[i] = 0u;
}

extern "C" void kernel_launch(void* const* d_in, const int* in_sizes, int n_in,
                              void* d_out, int out_size, void* d_ws, size_t ws_size,
                              hipStream_t stream)
{
    const float* labmap = (const float*)d_in[0];   // [L, N]
    const float* X      = (const float*)d_in[1];   // [D, N]
    const int N = in_sizes[0] / L;                 // 200000
    const int ntiles = N / TI;                     // 3125

    const size_t need = (size_t)NB * TBL * sizeof(unsigned);  // 6.3 MB
    if (d_ws && ws_size >= need && (N % TI) == 0) {
        unsigned* tables = (unsigned*)d_ws;
        labpool_main<<<NB, NT, 0, stream>>>(labmap, X, tables, N, ntiles);
        labpool_reduce<<<2 * D, 256, 0, stream>>>(tables, (float*)d_out, NB);
    } else {
        unsigned* gout = (unsigned*)d_out;
        zero_out_k<<<(D * L + 255) / 256, 256, 0, stream>>>(gout, D * L);
        labpool_fused_atomic<<<N / 400, 256, 0, stream>>>(labmap, X, gout, N);
    }
}

// Round 10
// 22.232 us; speedup vs baseline: 4.6009x; 1.0521x over previous
//
#include <hip/hip_runtime.h>

// LabPool: out[d,l] = max_n( labmap[l,n] * X[d,n] ), labmap one-hot over l.
// Zeros always participate -> out[d,l] = max(0, max_{label(n)=l} X[d,n]).
// Non-negative results -> uint bit ordering == float ordering (ds_max_u32).
//
// Locked-in lessons:
//  - NO hipLaunchCooperativeKernel (R4) and NO in-kernel cross-block handoff
//    (R8): per-block device-scope release fences serialize L2 writebacks at
//    ~0.25us/block. Kernel boundary = one flush. Two dispatches it is.
//  - lane = feature d, label wave-uniform at use (readlane) -> conflict-free DS.
//  - depth-2 register prefetch + double-buffered Xs, one barrier per tile.
//  - Occupancy sweep exhausted: 16 waves/CU (R7, 22.17us) beats 24 (R9,
//    23.39us) and ties 2-barrier variant (R6, 22.35us). Main kernel is at its
//    memory-latency floor; restore R7 best-known config.

constexpr int L = 32;
constexpr int D = 64;            // == wave size
constexpr int TI = 64;           // items/tile; 200000/64 = 3125 tiles
constexpr int NB = 512;          // blocks (2/CU co-resident)
constexpr int NT = 512;          // threads/block (8 waves)
constexpr int XS_STRIDE = 65;    // LDS X-tile row stride (2-way banks = free)
constexpr int SM_STRIDE = 33;    // LDS table row stride (2-way banks = free)
constexpr int SM_SIZE = D * SM_STRIDE;  // 2112
constexpr int TBL = D * L;       // packed global table (2048 u32)

__global__ __launch_bounds__(NT, 4)
void labpool_main(const float* __restrict__ labmap,
                  const float* __restrict__ X,
                  unsigned* __restrict__ tables, int N, int ntiles)
{
    __shared__ __attribute__((aligned(16))) float Xs[2][D * XS_STRIDE]; // 33 KB
    __shared__ unsigned sm[SM_SIZE];                                    // 8.4 KB

    const int tid  = threadIdx.x;
    const int wave = tid >> 6;
    const int lane = tid & 63;
    const int item  = lane & 7;              // decode: wave covers items wave*8..+7
    const int lrow0 = (lane >> 3) << 2;      // decode: 4 labmap rows per 8-lane group

    unsigned* dst = tables + (size_t)blockIdx.x * TBL;
    if ((int)blockIdx.x >= ntiles) {         // no tiles: emit zero table
        for (int i = tid; i < TBL; i += NT) dst[i] = 0u;
        return;
    }

    for (int i = tid; i < SM_SIZE; i += NT) sm[i] = 0u;

    const int r0 = tid >> 4;                 // staging rows 0..31
    const int c0 = 4 * (tid & 15);
    const int r1 = r0 + 32;                  // staging rows 32..63
    const size_t rowOff0 = (size_t)r0 * N + c0;
    const size_t rowOff1 = (size_t)r1 * N + c0;
    const float* mbase = labmap + (size_t)lrow0 * N + wave * 8 + item;

    const int laneX = lane * XS_STRIDE + wave * 8;
    const int laneS = lane * SM_STRIDE;

    float4 xr0, xr1;                         // single X register slot
    auto LOAD = [&](int t, float (&m)[4]) {
        const int n0 = t * TI;
        xr0 = *reinterpret_cast<const float4*>(X + rowOff0 + n0);
        xr1 = *reinterpret_cast<const float4*>(X + rowOff1 + n0);
        const float* mp = mbase + n0;
        m[0] = mp[0];
        m[1] = mp[(size_t)N];
        m[2] = mp[(size_t)2 * N];
        m[3] = mp[(size_t)3 * N];
    };
    auto STAGE = [&](int b) {
        *reinterpret_cast<float4*>(&Xs[b][r0 * XS_STRIDE + c0]) = xr0;
        *reinterpret_cast<float4*>(&Xs[b][r1 * XS_STRIDE + c0]) = xr1;
    };
    auto LABV = [&](const float (&m)[4]) -> unsigned {
        float acc =            (float)(lrow0)     * m[0];
        acc = fmaf((float)(lrow0 + 1), m[1], acc);
        acc = fmaf((float)(lrow0 + 2), m[2], acc);
        acc = fmaf((float)(lrow0 + 3), m[3], acc);
        acc += __shfl_xor(acc, 8);               // sum the 8 row-groups
        acc += __shfl_xor(acc, 16);
        acc += __shfl_xor(acc, 32);
        return (unsigned)acc;                    // exact small int
    };
    auto CONSUME = [&](int b, unsigned labv) {
#pragma unroll
        for (int j = 0; j < 8; ++j) {
            const int labj = __builtin_amdgcn_readlane((int)labv, j); // wave-uniform
            const float x = Xs[b][laneX + j];                          // 2-way banks
            atomicMax(&sm[laneS + labj], __float_as_uint(fmaxf(x, 0.f)));
        }
    };

    // ---- prologue: stage tile t into buf0, prefetch tile t+NB ----
    int t = blockIdx.x;
    float mA[4], mB[4];
    LOAD(t, mA);
    STAGE(0);
    unsigned lvA = LABV(mA);
    bool h1 = (t + NB < ntiles);
    if (h1) LOAD(t + NB, mB);
    __syncthreads();                             // buf0 ready

    while (true) {
        // ---- consume buf0 (tile t); stage tile t+NB -> buf1 ----
        if (h1) STAGE(1);                        // X regs hold tile t+NB
        const unsigned lvB = h1 ? LABV(mB) : 0u;
        if (t + 2 * NB < ntiles) LOAD(t + 2 * NB, mA);   // issue early
        CONSUME(0, lvA);
        __syncthreads();                         // stage(t+NB) done + consume(t) done
        if (!h1) break;
        t += NB;
        h1 = (t + NB < ntiles);

        // ---- consume buf1 (tile t); stage tile t+NB -> buf0 ----
        if (h1) STAGE(0);                        // X regs hold tile t+NB
        lvA = h1 ? LABV(mA) : 0u;
        if (t + 2 * NB < ntiles) LOAD(t + 2 * NB, mB);
        CONSUME(1, lvB);
        __syncthreads();
        if (!h1) break;
        t += NB;
        h1 = (t + NB < ntiles);
    }

    __syncthreads();                             // drain all waves' sm atomics
    for (int i = tid; i < TBL; i += NT)
        dst[i] = sm[(i >> 5) * SM_STRIDE + (i & 31)];   // unpad on the way out
}

__global__ __launch_bounds__(256)
void labpool_reduce(const unsigned* __restrict__ tables, float* __restrict__ out, int nb)
{
    // 128 blocks: block = (d, half). Each handles 16 labels = 4 uint4 parts.
    __shared__ uint4 red[256];
    const int tid  = threadIdx.x;
    const int d    = blockIdx.x >> 1;
    const int h    = blockIdx.x & 1;
    const int part = tid & 3;
    const int g    = tid >> 2;                   // 64 table-groups
    const int base = d * L + h * 16 + part * 4;  // 16-B aligned

    uint4 m = make_uint4(0u, 0u, 0u, 0u);
    for (int b = g; b < nb; b += 64) {
        const uint4 v = *reinterpret_cast<const uint4*>(tables + (size_t)b * TBL + base);
        m.x = (v.x > m.x) ? v.x : m.x;
        m.y = (v.y > m.y) ? v.y : m.y;
        m.z = (v.z > m.z) ? v.z : m.z;
        m.w = (v.w > m.w) ? v.w : m.w;
    }
    red[tid] = m;
    __syncthreads();
#pragma unroll
    for (int s = 128; s >= 4; s >>= 1) {
        if (tid < s) {
            const uint4 v = red[tid + s];
            uint4 r = red[tid];
            r.x = (v.x > r.x) ? v.x : r.x;
            r.y = (v.y > r.y) ? v.y : r.y;
            r.z = (v.z > r.z) ? v.z : r.z;
            r.w = (v.w > r.w) ? v.w : r.w;
            red[tid] = r;
        }
        __syncthreads();
    }
    if (tid < 4) {
        const uint4 r = red[tid];
        float4 f;
        f.x = __uint_as_float(r.x);
        f.y = __uint_as_float(r.y);
        f.z = __uint_as_float(r.z);
        f.w = __uint_as_float(r.w);
        *reinterpret_cast<float4*>(out + d * L + h * 16 + tid * 4) = f;
    }
}

// ---- fallback (tiny ws): fused kernel with global atomics ----
__global__ __launch_bounds__(256)
void labpool_fused_atomic(const float* __restrict__ labmap,
                          const float* __restrict__ X,
                          unsigned* __restrict__ gout, int N)
{
    __shared__ unsigned sm2[D * L];
    __shared__ unsigned char lab[400];
    const int tid = threadIdx.x;
    const int n0 = blockIdx.x * 400;
    for (int i = tid; i < D * L; i += 256) sm2[i] = 0u;
    constexpr int V = 100;
    for (int idx = tid; idx < L * V; idx += 256) {
        const int l = idx / V;
        const int v = idx - l * V;
        const float4 m = *reinterpret_cast<const float4*>(labmap + (size_t)l * N + n0 + 4 * v);
        if (m.x > 0.5f) lab[4 * v + 0] = (unsigned char)l;
        if (m.y > 0.5f) lab[4 * v + 1] = (unsigned char)l;
        if (m.z > 0.5f) lab[4 * v + 2] = (unsigned char)l;
        if (m.w > 0.5f) lab[4 * v + 3] = (unsigned char)l;
    }
    __syncthreads();
    for (int idx = tid; idx < D * V; idx += 256) {
        const int d = idx / V;
        const int v = idx - d * V;
        const float4 x = *reinterpret_cast<const float4*>(X + (size_t)d * N + n0 + 4 * v);
        const uchar4 lv = *reinterpret_cast<const uchar4*>(&lab[4 * v]);
        atomicMax(&sm2[d * L + lv.x], __float_as_uint(fmaxf(x.x, 0.f)));
        atomicMax(&sm2[d * L + lv.y], __float_as_uint(fmaxf(x.y, 0.f)));
        atomicMax(&sm2[d * L + lv.z], __float_as_uint(fmaxf(x.z, 0.f)));
        atomicMax(&sm2[d * L + lv.w], __float_as_uint(fmaxf(x.w, 0.f)));
    }
    __syncthreads();
    for (int i = tid; i < D * L; i += 256) atomicMax(&gout[i], sm2[i]);
}

__global__ void zero_out_k(unsigned* p, int n)
{
    const int i = blockIdx.x * 256 + threadIdx.x;
    if (i < n) p[i] = 0u;
}

extern "C" void kernel_launch(void* const* d_in, const int* in_sizes, int n_in,
                              void* d_out, int out_size, void* d_ws, size_t ws_size,
                              hipStream_t stream)
{
    const float* labmap = (const float*)d_in[0];   // [L, N]
    const float* X      = (const float*)d_in[1];   // [D, N]
    const int N = in_sizes[0] / L;                 // 200000
    const int ntiles = N / TI;                     // 3125

    const size_t need = (size_t)NB * TBL * sizeof(unsigned);  // 4.2 MB
    if (d_ws && ws_size >= need && (N % TI) == 0) {
        unsigned* tables = (unsigned*)d_ws;
        labpool_main<<<NB, NT, 0, stream>>>(labmap, X, tables, N, ntiles);
        labpool_reduce<<<2 * D, 256, 0, stream>>>(tables, (float*)d_out, NB);
    } else {
        unsigned* gout = (unsigned*)d_out;
        zero_out_k<<<(D * L + 255) / 256, 256, 0, stream>>>(gout, D * L);
        labpool_fused_atomic<<<N / 400, 256, 0, stream>>>(labmap, X, gout, N);
    }
}